// Round 3
// baseline (620.275 us; speedup 1.0000x reference)
//
#include <hip/hip_runtime.h>

// ---------------- problem constants (fixed shapes) ----------------
#define NTOT   2097152          // 1024*2048
#define NBLK   1024
#define NTHR   256
#define NIT    8                // NBLK*NTHR*NIT == NTOT
#define STRIDE (NBLK*NTHR)

// ---------------- ws layout (float offsets) ----------------
#define WS_SUMLR 0
#define WS_SUMD2 1
#define WPK   32      // pk   f32, 570
#define WPRK  608     // prk  f32, 300
#define WPB0  912     // pb[0], 30
#define WPB1  942     // pb[1], 30
#define WDT   976     // w_dt, 10
#define WDN   986
#define WBG   996
#define WBL   1006
#define WB4   1016    // b_dt, b_dn, b_bg, b_bl
#define WGAM  1020
#define WXB   1024    // 30: pb[0] + (h_tensor,h_global) columns folded in
#define P1    1088    // k_partial partials: NBLK*2
#define P2    3136    // k_main partials:    NBLK*24 (19 used)

// ---------------- out layout (float element offsets) ----------------
#define OFF_DELTA 0
#define OFF_GBAR  (NTOT)
#define OFF_LAM   (5*NTOT)
#define OFF_HP    (9*NTOT)
#define OFF_HT    (19*NTOT)
#define OFF_NU    (19*NTOT+5)
#define OFF_NUBAR (20*NTOT+5)
#define OFF_GI    (21*NTOT+5)

__device__ __forceinline__ float sigmoidf(float x) {
  return 1.0f / (1.0f + __expf(-x));
}
__device__ __forceinline__ float tanh_f(float x) {
  float ax = fabsf(x);
  float e  = __expf(-2.0f * ax);
  float t  = (1.0f - e) / (1.0f + e);
  return copysignf(t, x);
}

// ================= pass 1: partial sums of lr and d_theta^2 =================
__global__ __launch_bounds__(NTHR) void k_partial(
    const float* __restrict__ hparam,
    const float* __restrict__ lr,
    const float* __restrict__ wdt,
    const float* __restrict__ bdt,
    float* __restrict__ pout) {
  float w[10];
  #pragma unroll
  for (int k = 0; k < 10; ++k) w[k] = wdt[k];
  const float b0 = bdt[0];
  const int tid = blockIdx.x * NTHR + threadIdx.x;
  const float2* hp2 = (const float2*)hparam;
  float s_lr = 0.f, s_d2 = 0.f;
  #pragma unroll 1
  for (int it = 0; it < NIT; ++it) {
    const int i = tid + it * STRIDE;
    float d = b0;
    #pragma unroll
    for (int c = 0; c < 5; ++c) {
      const float2 v = hp2[i*5 + c];
      d = fmaf(v.x, w[2*c],   d);
      d = fmaf(v.y, w[2*c+1], d);
    }
    s_d2 = fmaf(d, d, s_d2);
    s_lr += lr[i];
  }
  #pragma unroll
  for (int off = 32; off > 0; off >>= 1) {
    s_lr += __shfl_down(s_lr, off);
    s_d2 += __shfl_down(s_d2, off);
  }
  __shared__ float lred[4][2];
  const int wid = threadIdx.x >> 6, lane = threadIdx.x & 63;
  if (lane == 0) { lred[wid][0] = s_lr; lred[wid][1] = s_d2; }
  __syncthreads();
  if (threadIdx.x == 0) {
    pout[blockIdx.x*2 + 0] = lred[0][0]+lred[1][0]+lred[2][0]+lred[3][0];
    pout[blockIdx.x*2 + 1] = lred[0][1]+lred[1][1]+lred[2][1]+lred[3][1];
  }
}

// ====== prep: copy weights into ws, fold const GRU cols, finalize sums ======
__global__ void k_prep(
    const float* __restrict__ pk,
    const float* __restrict__ prk,
    const float* __restrict__ pb,
    const float* __restrict__ wdt,
    const float* __restrict__ bdt,
    const float* __restrict__ wdn,
    const float* __restrict__ bdn,
    const float* __restrict__ wbg,
    const float* __restrict__ bbg,
    const float* __restrict__ wbl,
    const float* __restrict__ bbl,
    const float* __restrict__ ht,
    const float* __restrict__ hg,
    const float* __restrict__ gam,
    float* __restrict__ ws) {
  const int t = threadIdx.x;
  for (int idx = t; idx < 570; idx += 256) ws[WPK  + idx] = pk[idx];
  for (int idx = t; idx < 300; idx += 256) ws[WPRK + idx] = prk[idx];
  if (t < 60) ws[WPB0 + t] = pb[t];   // pb[0] and pb[1] (WPB1 = WPB0+30)
  if (t < 10) {
    ws[WDT+t] = wdt[t]; ws[WDN+t] = wdn[t];
    ws[WBG+t] = wbg[t]; ws[WBL+t] = wbl[t];
  }
  if (t == 0) {
    ws[WB4+0] = bdt[0]; ws[WB4+1] = bdn[0];
    ws[WB4+2] = bbg[0]; ws[WB4+3] = bbl[0];
    ws[WGAM]  = gam[0];
  }
  if (t < 30) {  // xs base: pb[0][t] + sum_k ht[k]*pk[9+k][t] + hg[k]*pk[14+k][t]
    float v = pb[t];
    #pragma unroll
    for (int k = 0; k < 5; ++k) v = fmaf(ht[k], pk[(9+k)*30 + t], v);
    #pragma unroll
    for (int k = 0; k < 5; ++k) v = fmaf(hg[k], pk[(14+k)*30 + t], v);
    ws[WXB + t] = v;
  }
  // finalize the two global sums from P1
  float a = 0.f, b = 0.f;
  for (int idx = t; idx < NBLK; idx += 256) {
    a += ws[P1 + 2*idx];
    b += ws[P1 + 2*idx + 1];
  }
  #pragma unroll
  for (int off = 32; off > 0; off >>= 1) {
    a += __shfl_down(a, off);
    b += __shfl_down(b, off);
  }
  __shared__ float lred[4][2];
  const int wid = t >> 6, lane = t & 63;
  if (lane == 0) { lred[wid][0] = a; lred[wid][1] = b; }
  __syncthreads();
  if (t == 0) {
    ws[WS_SUMLR] = lred[0][0]+lred[1][0]+lred[2][0]+lred[3][0];
    ws[WS_SUMD2] = lred[0][1]+lred[1][1]+lred[2][1]+lred[3][1];
  }
}

// ================= main per-element kernel =================
__global__ __launch_bounds__(NTHR) void k_main(
    const float* __restrict__ grads,
    const float* __restrict__ gbar,
    const float* __restrict__ lam,
    const float* __restrict__ hparam,
    const float* __restrict__ nubar,
    const float* __restrict__ lr,
    const float* __restrict__ cw,      // ws (weights + sums), read-only here
    float* __restrict__ pout,          // ws + P2
    float* __restrict__ out) {
  const float mean_lr = cw[WS_SUMLR] * (1.0f / (float)NTOT);
  const float scale   = (float)NTOT / sqrtf(cw[WS_SUMD2]);
  const float gamma   = cw[WGAM];

  float am0=0,am1=0,am2=0,am3=0, ag0=0,ag1=0,ag2=0,ag3=0, anu=0;
  float ah[10];
  #pragma unroll
  for (int j = 0; j < 10; ++j) ah[j] = 0.f;

  const int tid = blockIdx.x * NTHR + threadIdx.x;
  const float2* hp2  = (const float2*)hparam;
  float2*       hpo2 = (float2*)(out + OFF_HP);

  #pragma unroll 1
  for (int it = 0; it < NIT; ++it) {
    const int i = tid + it * STRIDE;
    // -------- loads --------
    float h[10];
    #pragma unroll
    for (int c = 0; c < 5; ++c) {
      const float2 v = hp2[i*5 + c];
      h[2*c]   = v.x;
      h[2*c+1] = v.y;
    }
    const float g   = grads[i];
    const float lri = lr[i];
    const float nb  = nubar[i];

    // -------- 10-dim dots --------
    float ddt = cw[WB4+0], ddn = cw[WB4+1], dbg = cw[WB4+2], dbl = cw[WB4+3];
    #pragma unroll
    for (int k = 0; k < 10; ++k) {
      ddt = fmaf(h[k], cw[WDT+k], ddt);
      ddn = fmaf(h[k], cw[WDN+k], ddn);
      dbg = fmaf(h[k], cw[WBG+k], dbg);
      dbl = fmaf(h[k], cw[WBL+k], dbl);
    }
    const float bg = sigmoidf(dbg);
    const float bl = sigmoidf(dbl);

    // -------- per-scale EMA, m, gamma_feat --------
    const float g2 = g * g;
    float x[9], ll[4];
    float b1 = bg, b2 = bl, llsum = 0.f;
    #pragma unroll
    for (int s = 0; s < 4; ++s) {
      if (s) { b1 = sqrtf(b1); b2 = sqrtf(b2); }   // beta^(0.5^s)
      const float gb = b1 * gbar[s*NTOT + i] + (1.0f - b1) * g;
      const float lm = b2 * lam [s*NTOT + i] + (1.0f - b2) * g2;
      out[OFF_GBAR + s*NTOT + i] = gb;
      out[OFF_LAM  + s*NTOT + i] = lm;
      x[s]  = gb * rsqrtf(lm);
      ll[s] = __logf(lm);
      llsum += ll[s];
    }
    am0 += x[0]; am1 += x[1]; am2 += x[2]; am3 += x[3];
    const float llm = llsum * 0.25f;
    x[4] = ll[0]-llm; x[5] = ll[1]-llm; x[6] = ll[2]-llm; x[7] = ll[3]-llm;
    ag0 += x[4]; ag1 += x[5]; ag2 += x[6]; ag3 += x[7];

    // -------- nu / nu_bar_new / delta_theta --------
    const float nu = ddn + nb;
    out[OFF_NU    + i] = nu;
    out[OFF_NUBAR + i] = gamma*nb + (1.0f - gamma)*nu;
    out[OFF_DELTA + i] = __expf(lri) * ddt * scale;
    const float nurel = lri - mean_lr;
    x[8] = nurel;
    anu += nurel;

    // -------- per-parameter GRU --------
    float xs[30];
    #pragma unroll
    for (int j = 0; j < 30; ++j) xs[j] = cw[WXB + j];
    #pragma unroll
    for (int k = 0; k < 9; ++k) {
      const float xk = x[k];
      #pragma unroll
      for (int j = 0; j < 30; ++j) xs[j] = fmaf(xk, cw[WPK + k*30 + j], xs[j]);
    }
    #pragma unroll
    for (int jj = 0; jj < 5; ++jj) {
      float2 hnew;
      #pragma unroll
      for (int half = 0; half < 2; ++half) {
        const int j = 2*jj + half;
        float rz = cw[WPB1 + j], rr = cw[WPB1 + 10 + j], rh = cw[WPB1 + 20 + j];
        #pragma unroll
        for (int k = 0; k < 10; ++k) {
          const float hk = h[k];
          rz = fmaf(hk, cw[WPRK + k*30 + j],      rz);
          rr = fmaf(hk, cw[WPRK + k*30 + 10 + j], rr);
          rh = fmaf(hk, cw[WPRK + k*30 + 20 + j], rh);
        }
        const float z  = sigmoidf(xs[j] + rz);
        const float r  = sigmoidf(xs[10+j] + rr);
        const float hh = tanh_f(xs[20+j] + r*rh);
        const float hn = z*h[j] + (1.0f - z)*hh;
        ah[j] += hn;
        if (half == 0) hnew.x = hn; else hnew.y = hn;
      }
      hpo2[i*5 + jj] = hnew;
    }
  }

  // -------- block reduction of the 19 partials --------
  float acc[19];
  acc[0]=am0; acc[1]=am1; acc[2]=am2; acc[3]=am3;
  acc[4]=ag0; acc[5]=ag1; acc[6]=ag2; acc[7]=ag3;
  acc[8]=anu;
  #pragma unroll
  for (int j = 0; j < 10; ++j) acc[9+j] = ah[j];
  #pragma unroll
  for (int off = 32; off > 0; off >>= 1) {
    #pragma unroll
    for (int v = 0; v < 19; ++v) acc[v] += __shfl_down(acc[v], off);
  }
  __shared__ float lred[4][19];
  const int wid = threadIdx.x >> 6, lane = threadIdx.x & 63;
  if (lane == 0) {
    #pragma unroll
    for (int v = 0; v < 19; ++v) lred[wid][v] = acc[v];
  }
  __syncthreads();
  if (threadIdx.x < 19) {
    const int v = threadIdx.x;
    pout[blockIdx.x*24 + v] = lred[0][v]+lred[1][v]+lred[2][v]+lred[3][v];
  }
}

// ================= final: 19 means, tensor GRU, tail outputs =================
__global__ void k_final(
    const float* __restrict__ tk,
    const float* __restrict__ trk,
    const float* __restrict__ tb,
    const float* __restrict__ ht,
    const float* __restrict__ hg,
    const float* __restrict__ p2,
    float* __restrict__ out) {
  const int t = threadIdx.x;
  float acc[19];
  #pragma unroll
  for (int v = 0; v < 19; ++v) acc[v] = 0.f;
  for (int b = t; b < NBLK; b += 256) {
    #pragma unroll
    for (int v = 0; v < 19; ++v) acc[v] += p2[b*24 + v];
  }
  #pragma unroll
  for (int off = 32; off > 0; off >>= 1) {
    #pragma unroll
    for (int v = 0; v < 19; ++v) acc[v] += __shfl_down(acc[v], off);
  }
  __shared__ float lred[4][19];
  const int wid = t >> 6, lane = t & 63;
  if (lane == 0) {
    #pragma unroll
    for (int v = 0; v < 19; ++v) lred[wid][v] = acc[v];
  }
  __syncthreads();
  if (t == 0) {
    const float invn = 1.0f / (float)NTOT;
    float ti[24];
    #pragma unroll
    for (int v = 0; v < 19; ++v)
      ti[v] = (lred[0][v]+lred[1][v]+lred[2][v]+lred[3][v]) * invn;
    #pragma unroll
    for (int k = 0; k < 5; ++k) ti[19+k] = hg[k];
    float h5[5];
    #pragma unroll
    for (int k = 0; k < 5; ++k) h5[k] = ht[k];

    float xs[15];
    #pragma unroll
    for (int j = 0; j < 15; ++j) {
      float v = tb[j];
      #pragma unroll
      for (int k = 0; k < 24; ++k) v = fmaf(ti[k], tk[k*15 + j], v);
      xs[j] = v;
    }
    float htn[5];
    #pragma unroll
    for (int j = 0; j < 5; ++j) {
      float rz = tb[15 + j], rr = tb[20 + j], rh = tb[25 + j];
      #pragma unroll
      for (int k = 0; k < 5; ++k) {
        rz = fmaf(h5[k], trk[k*15 + j],      rz);
        rr = fmaf(h5[k], trk[k*15 + 5 + j],  rr);
        rh = fmaf(h5[k], trk[k*15 + 10 + j], rh);
      }
      const float z  = sigmoidf(xs[j] + rz);
      const float r  = sigmoidf(xs[5+j] + rr);
      const float hh = tanh_f(xs[10+j] + r*rh);
      htn[j] = z*h5[j] + (1.0f - z)*hh;
      out[OFF_HT + j] = htn[j];
    }
    #pragma unroll
    for (int v = 0; v < 19; ++v) out[OFF_GI + v] = ti[v];
    #pragma unroll
    for (int k = 0; k < 5; ++k)  out[OFF_GI + 19 + k] = htn[k];
  }
}

extern "C" void kernel_launch(void* const* d_in, const int* in_sizes, int n_in,
                              void* d_out, int out_size, void* d_ws, size_t ws_size,
                              hipStream_t stream) {
  const float* grads  = (const float*)d_in[1];
  const float* gbar   = (const float*)d_in[2];
  const float* lam    = (const float*)d_in[3];
  const float* hparam = (const float*)d_in[4];
  const float* ht     = (const float*)d_in[5];
  const float* hg     = (const float*)d_in[6];
  const float* nubar  = (const float*)d_in[7];
  const float* lr     = (const float*)d_in[8];
  const float* pk     = (const float*)d_in[9];
  const float* prk    = (const float*)d_in[10];
  const float* pb     = (const float*)d_in[11];
  const float* tk     = (const float*)d_in[12];
  const float* trk    = (const float*)d_in[13];
  const float* tb     = (const float*)d_in[14];
  const float* wdt    = (const float*)d_in[15];
  const float* bdt    = (const float*)d_in[16];
  const float* wdn    = (const float*)d_in[17];
  const float* bdn    = (const float*)d_in[18];
  const float* wbg    = (const float*)d_in[19];
  const float* bbg    = (const float*)d_in[20];
  const float* wbl    = (const float*)d_in[21];
  const float* bbl    = (const float*)d_in[22];
  const float* gam    = (const float*)d_in[23];
  float* ws = (float*)d_ws;
  float* out = (float*)d_out;

  k_partial<<<NBLK, NTHR, 0, stream>>>(hparam, lr, wdt, bdt, ws + P1);
  k_prep<<<1, 256, 0, stream>>>(pk, prk, pb, wdt, bdt, wdn, bdn,
                                wbg, bbg, wbl, bbl, ht, hg, gam, ws);
  k_main<<<NBLK, NTHR, 0, stream>>>(grads, gbar, lam, hparam, nubar, lr,
                                    ws, ws + P2, out);
  k_final<<<1, 256, 0, stream>>>(tk, trk, tb, ht, hg, ws + P2, out);
}

// Round 4
// 594.804 us; speedup vs baseline: 1.0428x; 1.0428x over previous
//
#include <hip/hip_runtime.h>

// ---------------- problem constants ----------------
#define NTOT   2097152          // 1024*2048
#define NBLK   1024
#define NTHR   256
#define NIT    8
#define STRIDE (NBLK*NTHR)

// ---------------- ws layout (float offsets) ----------------
#define WS_SUMLR 0
#define WS_SUMD2 1
#define WGAM     2
#define WB4      4     // float4: bdt, bdn, bbg, bbl
#define WSM      8     // 10 x float4: (wdt,wdn,wbg,wbl)[k]
#define WROW     48    // 20 rows x 40 floats (16B-aligned rows)
#define WEND     848
#define P1       896   // k_partial partials: NBLK*2
#define P2       2944  // k_main partials: NBLK*24

// ---------------- out layout (float offsets) ----------------
#define OFF_DELTA 0
#define OFF_GBAR  (NTOT)
#define OFF_LAM   (5*NTOT)
#define OFF_HP    (9*NTOT)
#define OFF_HT    (19*NTOT)
#define OFF_NU    (19*NTOT+5)
#define OFF_NUBAR (20*NTOT+5)
#define OFF_GI    (21*NTOT+5)

__device__ __forceinline__ float fast_rcp(float x)  { return __builtin_amdgcn_rcpf(x); }
__device__ __forceinline__ float fast_rsq(float x)  { return __builtin_amdgcn_rsqf(x); }
__device__ __forceinline__ float fast_sqrt(float x) { return __builtin_amdgcn_sqrtf(x); }
__device__ __forceinline__ float sigmoidf(float x) {
  return fast_rcp(1.0f + __expf(-x));          // v_exp + v_add + v_rcp (+mul)
}
__device__ __forceinline__ float tanh_f(float x) {
  // tanh(x) = 2/(1+exp(-2x)) - 1 ; saturates correctly for |x| large
  const float e = __expf(-2.0f * x);
  return fmaf(2.0f, fast_rcp(1.0f + e), -1.0f);
}

// ================= pass 1: partial sums of lr and d_theta^2 =================
__global__ __launch_bounds__(NTHR) void k_partial(
    const float* __restrict__ hparam,
    const float* __restrict__ lr,
    const float* __restrict__ wdt,
    const float* __restrict__ bdt,
    float* __restrict__ pout) {
  float w[10];
  #pragma unroll
  for (int k = 0; k < 10; ++k) w[k] = wdt[k];
  const float b0 = bdt[0];
  const int tid = blockIdx.x * NTHR + threadIdx.x;
  const float2* hp2 = (const float2*)hparam;
  float s_lr = 0.f, s_d2 = 0.f;
  #pragma unroll 1
  for (int it = 0; it < NIT; ++it) {
    const int i = tid + it * STRIDE;
    float d = b0;
    #pragma unroll
    for (int c = 0; c < 5; ++c) {
      const float2 v = hp2[i*5 + c];
      d = fmaf(v.x, w[2*c],   d);
      d = fmaf(v.y, w[2*c+1], d);
    }
    s_d2 = fmaf(d, d, s_d2);
    s_lr += lr[i];
  }
  #pragma unroll
  for (int off = 32; off > 0; off >>= 1) {
    s_lr += __shfl_down(s_lr, off);
    s_d2 += __shfl_down(s_d2, off);
  }
  __shared__ float lred[4][2];
  const int wid = threadIdx.x >> 6, lane = threadIdx.x & 63;
  if (lane == 0) { lred[wid][0] = s_lr; lred[wid][1] = s_d2; }
  __syncthreads();
  if (threadIdx.x == 0) {
    pout[blockIdx.x*2 + 0] = lred[0][0]+lred[1][0]+lred[2][0]+lred[3][0];
    pout[blockIdx.x*2 + 1] = lred[0][1]+lred[1][1]+lred[2][1]+lred[3][1];
  }
}

// ====== prep: build padded fused weight rows in ws, finalize global sums ======
// Row layout (40 floats each, rows at WROW):
//   rows 0..8   (x-feature k):  [pk[k][0..19] | pk[k][20..29] | 0 x10]
//   rows 9..18  (h-feature k):  [prk[k][0..19] | 0 x10 | prk[k][20..29]]
//   row  19     (bias/init):    [xb[0..19]+pb1[0..19] | xb[20..29] | pb1[20..29]]
// where xb[c] = pb0[c] + sum_k ht[k]*pk[9+k][c] + hg[k]*pk[14+k][c]
__global__ void k_prep(
    const float* __restrict__ pk,
    const float* __restrict__ prk,
    const float* __restrict__ pb,
    const float* __restrict__ wdt,
    const float* __restrict__ bdt,
    const float* __restrict__ wdn,
    const float* __restrict__ bdn,
    const float* __restrict__ wbg,
    const float* __restrict__ bbg,
    const float* __restrict__ wbl,
    const float* __restrict__ bbl,
    const float* __restrict__ ht,
    const float* __restrict__ hg,
    const float* __restrict__ gam,
    float* __restrict__ ws) {
  const int t = threadIdx.x;
  for (int idx = t; idx < 800; idx += NTHR) {
    const int r = idx / 40, c = idx - r*40;
    float v = 0.f;
    if (r < 9) {
      if (c < 30) v = pk[r*30 + c];
    } else if (r < 19) {
      const int k = r - 9;
      if (c < 20)       v = prk[k*30 + c];
      else if (c >= 30) v = prk[k*30 + (c - 10)];
    } else {
      if (c < 30) {
        float xb = pb[c];
        #pragma unroll
        for (int k = 0; k < 5; ++k) xb = fmaf(ht[k], pk[(9+k)*30 + c], xb);
        #pragma unroll
        for (int k = 0; k < 5; ++k) xb = fmaf(hg[k], pk[(14+k)*30 + c], xb);
        v = (c < 20) ? (xb + pb[30 + c]) : xb;
      } else {
        v = pb[30 + (c - 10)];   // pb1[20 + (c-30)]
      }
    }
    ws[WROW + idx] = v;
  }
  if (t < 10) {
    ws[WSM + t*4 + 0] = wdt[t];
    ws[WSM + t*4 + 1] = wdn[t];
    ws[WSM + t*4 + 2] = wbg[t];
    ws[WSM + t*4 + 3] = wbl[t];
  }
  if (t == 0) {
    ws[WGAM]  = gam[0];
    ws[WB4+0] = bdt[0]; ws[WB4+1] = bdn[0];
    ws[WB4+2] = bbg[0]; ws[WB4+3] = bbl[0];
  }
  // finalize the two global sums from P1
  float a = 0.f, b = 0.f;
  for (int idx = t; idx < NBLK; idx += NTHR) {
    a += ws[P1 + 2*idx];
    b += ws[P1 + 2*idx + 1];
  }
  #pragma unroll
  for (int off = 32; off > 0; off >>= 1) {
    a += __shfl_down(a, off);
    b += __shfl_down(b, off);
  }
  __shared__ float lred[4][2];
  const int wid = t >> 6, lane = t & 63;
  if (lane == 0) { lred[wid][0] = a; lred[wid][1] = b; }
  __syncthreads();
  if (t == 0) {
    ws[WS_SUMLR] = lred[0][0]+lred[1][0]+lred[2][0]+lred[3][0];
    ws[WS_SUMD2] = lred[0][1]+lred[1][1]+lred[2][1]+lred[3][1];
  }
}

// ================= main per-element kernel =================
__global__ __launch_bounds__(NTHR) void k_main(
    const float* __restrict__ grads,
    const float* __restrict__ gbar,
    const float* __restrict__ lam,
    const float* __restrict__ hparam,
    const float* __restrict__ nubar,
    const float* __restrict__ lr,
    const float* __restrict__ cw,      // ws
    float* __restrict__ pout,          // ws + P2
    float* __restrict__ out) {
  __shared__ float sw[WEND];
  for (int idx = threadIdx.x; idx < WEND; idx += NTHR) sw[idx] = cw[idx];
  __syncthreads();

  const float mean_lr = sw[WS_SUMLR] * (1.0f / (float)NTOT);
  const float scale   = (float)NTOT * fast_rsq(sw[WS_SUMD2]);
  const float gamma   = sw[WGAM];
  const float4 b4     = *(const float4*)&sw[WB4];

  float am0=0,am1=0,am2=0,am3=0, ag0=0,ag1=0,ag2=0,ag3=0, anu=0;
  float ah[10];
  #pragma unroll
  for (int j = 0; j < 10; ++j) ah[j] = 0.f;

  const int tid = blockIdx.x * NTHR + threadIdx.x;
  const float2* hp2  = (const float2*)hparam;
  float2*       hpo2 = (float2*)(out + OFF_HP);

  #pragma unroll 1
  for (int it = 0; it < NIT; ++it) {
    const int i = tid + it * STRIDE;
    // -------- loads --------
    float h[10];
    #pragma unroll
    for (int c = 0; c < 5; ++c) {
      const float2 v = hp2[i*5 + c];
      h[2*c]   = v.x;
      h[2*c+1] = v.y;
    }
    const float g   = grads[i];
    const float lri = lr[i];
    const float nb  = nubar[i];

    // -------- 4 small dots via float4 rows (LDS broadcast b128) --------
    float4 d = b4;
    #pragma unroll
    for (int k = 0; k < 10; ++k) {
      const float4 w = *(const float4*)&sw[WSM + 4*k];
      d.x = fmaf(h[k], w.x, d.x);   // ddt
      d.y = fmaf(h[k], w.y, d.y);   // ddn
      d.z = fmaf(h[k], w.z, d.z);   // dbg
      d.w = fmaf(h[k], w.w, d.w);   // dbl
    }
    const float bg = sigmoidf(d.z);
    const float bl = sigmoidf(d.w);

    // -------- per-scale EMA, m, gamma_feat --------
    const float g2 = g * g;
    float x[9], ll[4];
    float b1 = bg, b2 = bl;
    #pragma unroll
    for (int s = 0; s < 4; ++s) {
      if (s) { b1 = fast_sqrt(b1); b2 = fast_sqrt(b2); }
      const float go = gbar[s*NTOT + i];
      const float lo = lam [s*NTOT + i];
      const float gb = fmaf(b1, go - g,  g);
      const float lm = fmaf(b2, lo - g2, g2);
      out[OFF_GBAR + s*NTOT + i] = gb;
      out[OFF_LAM  + s*NTOT + i] = lm;
      x[s]  = gb * fast_rsq(lm);
      ll[s] = __logf(lm);
    }
    am0 += x[0]; am1 += x[1]; am2 += x[2]; am3 += x[3];
    const float llm = (ll[0]+ll[1]+ll[2]+ll[3]) * 0.25f;
    x[4] = ll[0]-llm; x[5] = ll[1]-llm; x[6] = ll[2]-llm; x[7] = ll[3]-llm;
    ag0 += x[4]; ag1 += x[5]; ag2 += x[6]; ag3 += x[7];

    // -------- nu / nu_bar_new / delta_theta --------
    const float nu = d.y + nb;
    out[OFF_NU    + i] = nu;
    out[OFF_NUBAR + i] = fmaf(gamma, nb - nu, nu);   // gamma*nb + (1-gamma)*nu
    out[OFF_DELTA + i] = __expf(lri) * d.x * scale;
    const float nurel = lri - mean_lr;
    x[8] = nurel;
    anu += nurel;

    // -------- fused GRU matmul: a[0..19]=xz+rz|xr+rr, a[20..29]=xh, a[30..39]=rh --------
    float a[40];
    {
      const float4* br = (const float4*)&sw[WROW + 19*40];
      #pragma unroll
      for (int q = 0; q < 10; ++q) {
        const float4 b = br[q];
        a[4*q+0]=b.x; a[4*q+1]=b.y; a[4*q+2]=b.z; a[4*q+3]=b.w;
      }
    }
    #pragma unroll
    for (int k = 0; k < 19; ++k) {
      const float fk = (k < 9) ? x[k] : h[k-9];
      const float4* wr = (const float4*)&sw[WROW + k*40];
      #pragma unroll
      for (int q = 0; q < 10; ++q) {
        const float4 w = wr[q];
        a[4*q+0] = fmaf(fk, w.x, a[4*q+0]);
        a[4*q+1] = fmaf(fk, w.y, a[4*q+1]);
        a[4*q+2] = fmaf(fk, w.z, a[4*q+2]);
        a[4*q+3] = fmaf(fk, w.w, a[4*q+3]);
      }
    }

    // -------- gates --------
    float hn[10];
    #pragma unroll
    for (int u = 0; u < 10; ++u) {
      const float z   = sigmoidf(a[u]);
      const float r   = sigmoidf(a[10+u]);
      const float pre = fmaf(r, a[30+u], a[20+u]);
      const float th  = tanh_f(pre);
      hn[u] = fmaf(z, h[u] - th, th);   // z*h + (1-z)*th
      ah[u] += hn[u];
    }
    #pragma unroll
    for (int jj = 0; jj < 5; ++jj)
      hpo2[i*5 + jj] = make_float2(hn[2*jj], hn[2*jj+1]);
  }

  // -------- block reduction of the 19 partials --------
  float acc[19];
  acc[0]=am0; acc[1]=am1; acc[2]=am2; acc[3]=am3;
  acc[4]=ag0; acc[5]=ag1; acc[6]=ag2; acc[7]=ag3;
  acc[8]=anu;
  #pragma unroll
  for (int j = 0; j < 10; ++j) acc[9+j] = ah[j];
  #pragma unroll
  for (int off = 32; off > 0; off >>= 1) {
    #pragma unroll
    for (int v = 0; v < 19; ++v) acc[v] += __shfl_down(acc[v], off);
  }
  __shared__ float lred[4][19];
  const int wid = threadIdx.x >> 6, lane = threadIdx.x & 63;
  if (lane == 0) {
    #pragma unroll
    for (int v = 0; v < 19; ++v) lred[wid][v] = acc[v];
  }
  __syncthreads();
  if (threadIdx.x < 19) {
    const int v = threadIdx.x;
    pout[blockIdx.x*24 + v] = lred[0][v]+lred[1][v]+lred[2][v]+lred[3][v];
  }
}

// ================= final: 19 means, tensor GRU, tail outputs =================
__global__ void k_final(
    const float* __restrict__ tk,
    const float* __restrict__ trk,
    const float* __restrict__ tb,
    const float* __restrict__ ht,
    const float* __restrict__ hg,
    const float* __restrict__ p2,
    float* __restrict__ out) {
  const int t = threadIdx.x;
  float acc[19];
  #pragma unroll
  for (int v = 0; v < 19; ++v) acc[v] = 0.f;
  for (int b = t; b < NBLK; b += NTHR) {
    #pragma unroll
    for (int v = 0; v < 19; ++v) acc[v] += p2[b*24 + v];
  }
  #pragma unroll
  for (int off = 32; off > 0; off >>= 1) {
    #pragma unroll
    for (int v = 0; v < 19; ++v) acc[v] += __shfl_down(acc[v], off);
  }
  __shared__ float lred[4][19];
  const int wid = t >> 6, lane = t & 63;
  if (lane == 0) {
    #pragma unroll
    for (int v = 0; v < 19; ++v) lred[wid][v] = acc[v];
  }
  __syncthreads();
  if (t == 0) {
    const float invn = 1.0f / (float)NTOT;
    float ti[24];
    #pragma unroll
    for (int v = 0; v < 19; ++v)
      ti[v] = (lred[0][v]+lred[1][v]+lred[2][v]+lred[3][v]) * invn;
    #pragma unroll
    for (int k = 0; k < 5; ++k) ti[19+k] = hg[k];
    float h5[5];
    #pragma unroll
    for (int k = 0; k < 5; ++k) h5[k] = ht[k];

    float xs[15];
    #pragma unroll
    for (int j = 0; j < 15; ++j) {
      float v = tb[j];
      #pragma unroll
      for (int k = 0; k < 24; ++k) v = fmaf(ti[k], tk[k*15 + j], v);
      xs[j] = v;
    }
    float htn[5];
    #pragma unroll
    for (int j = 0; j < 5; ++j) {
      float rz = tb[15 + j], rr = tb[20 + j], rh = tb[25 + j];
      #pragma unroll
      for (int k = 0; k < 5; ++k) {
        rz = fmaf(h5[k], trk[k*15 + j],      rz);
        rr = fmaf(h5[k], trk[k*15 + 5 + j],  rr);
        rh = fmaf(h5[k], trk[k*15 + 10 + j], rh);
      }
      const float z  = sigmoidf(xs[j] + rz);
      const float r  = sigmoidf(xs[5+j] + rr);
      const float hh = tanh_f(xs[10+j] + r*rh);
      htn[j] = fmaf(z, h5[j] - hh, hh);
      out[OFF_HT + j] = htn[j];
    }
    #pragma unroll
    for (int v = 0; v < 19; ++v) out[OFF_GI + v] = ti[v];
    #pragma unroll
    for (int k = 0; k < 5; ++k)  out[OFF_GI + 19 + k] = htn[k];
  }
}

extern "C" void kernel_launch(void* const* d_in, const int* in_sizes, int n_in,
                              void* d_out, int out_size, void* d_ws, size_t ws_size,
                              hipStream_t stream) {
  const float* grads  = (const float*)d_in[1];
  const float* gbar   = (const float*)d_in[2];
  const float* lam    = (const float*)d_in[3];
  const float* hparam = (const float*)d_in[4];
  const float* ht     = (const float*)d_in[5];
  const float* hg     = (const float*)d_in[6];
  const float* nubar  = (const float*)d_in[7];
  const float* lr     = (const float*)d_in[8];
  const float* pk     = (const float*)d_in[9];
  const float* prk    = (const float*)d_in[10];
  const float* pb     = (const float*)d_in[11];
  const float* tk     = (const float*)d_in[12];
  const float* trk    = (const float*)d_in[13];
  const float* tb     = (const float*)d_in[14];
  const float* wdt    = (const float*)d_in[15];
  const float* bdt    = (const float*)d_in[16];
  const float* wdn    = (const float*)d_in[17];
  const float* bdn    = (const float*)d_in[18];
  const float* wbg    = (const float*)d_in[19];
  const float* bbg    = (const float*)d_in[20];
  const float* wbl    = (const float*)d_in[21];
  const float* bbl    = (const float*)d_in[22];
  const float* gam    = (const float*)d_in[23];
  float* ws  = (float*)d_ws;
  float* out = (float*)d_out;

  k_partial<<<NBLK, NTHR, 0, stream>>>(hparam, lr, wdt, bdt, ws + P1);
  k_prep<<<1, NTHR, 0, stream>>>(pk, prk, pb, wdt, bdt, wdn, bdn,
                                 wbg, bbg, wbl, bbl, ht, hg, gam, ws);
  k_main<<<NBLK, NTHR, 0, stream>>>(grads, gbar, lam, hparam, nubar, lr,
                                    ws, ws + P2, out);
  k_final<<<1, NTHR, 0, stream>>>(tk, trk, tb, ht, hg, ws + P2, out);
}